// Round 3
// baseline (187.166 us; speedup 1.0000x reference)
//
#include <hip/hip_runtime.h>
#include <hip/hip_bf16.h>

#define BB 32
#define SS 1600
#define DD 128
#define DFFN 2048
#define S2N 3200
#define RS 136  // LDS row stride in bf16 elems (128 + 8 pad -> conflict-free-ish b128 reads)

typedef __attribute__((ext_vector_type(8))) short short8;
typedef __attribute__((ext_vector_type(4))) float floatx4;
typedef unsigned int u32;
typedef unsigned short u16;

__device__ __forceinline__ u32 encf(float f) {
  u32 u = __float_as_uint(f);
  return (u & 0x80000000u) ? ~u : (u | 0x80000000u);
}
__device__ __forceinline__ float decf(u32 e) {
  u32 u = (e & 0x80000000u) ? (e & 0x7fffffffu) : ~e;
  return __uint_as_float(u);
}
__device__ __forceinline__ u16 f2b(float x) {
  __hip_bfloat16 h = __float2bfloat16(x);
  return __builtin_bit_cast(u16, h);
}
__device__ __forceinline__ float b2f(u16 h) { return __uint_as_float(((u32)h) << 16); }

// ---------------- K0: gTb[t][s] = bf16(sigmoid(se[s][t])); init m1u/m2u ----------------
__global__ __launch_bounds__(256) void k_init(const float* __restrict__ se,
                                              u16* __restrict__ gTb,
                                              u32* __restrict__ m1u,
                                              u32* __restrict__ m2u) {
  __shared__ float t64[64][65];
  int bx = blockIdx.x % 25, by = blockIdx.x / 25;
  int r0 = by * 64, c0 = bx * 64;
  int tr = threadIdx.x >> 4, tc4 = (threadIdx.x & 15) * 4;
  for (int p = 0; p < 4; ++p) {
    int r = p * 16 + tr;
    float4 v = *(const float4*)(se + (size_t)(r0 + r) * SS + c0 + tc4);
    t64[r][tc4 + 0] = 1.f / (1.f + __expf(-v.x));
    t64[r][tc4 + 1] = 1.f / (1.f + __expf(-v.y));
    t64[r][tc4 + 2] = 1.f / (1.f + __expf(-v.z));
    t64[r][tc4 + 3] = 1.f / (1.f + __expf(-v.w));
  }
  __syncthreads();
  for (int p = 0; p < 4; ++p) {
    int c = p * 16 + tr;  // output row = c0 + c
    ushort4 o;
    o.x = f2b(t64[tc4 + 0][c]);
    o.y = f2b(t64[tc4 + 1][c]);
    o.z = f2b(t64[tc4 + 2][c]);
    o.w = f2b(t64[tc4 + 3][c]);
    *(ushort4*)(gTb + (size_t)(c0 + c) * SS + r0 + tc4) = o;
  }
  int i = blockIdx.x * 256 + threadIdx.x;
  if (i < BB * SS) {  // 0 encodes "below every finite float" in the monotonic map
    m1u[i] = 0u;
    m2u[i] = 0u;
  }
}

// ---------------- K1: q/k projection + l2norm (bf16 MFMA) ----------------
__global__ __launch_bounds__(256) void k_proj(const float* __restrict__ tgt,
                                              const float* __restrict__ memin,
                                              const float* __restrict__ w1,
                                              const float* __restrict__ b1,
                                              u16* __restrict__ qb, u16* __restrict__ kb) {
  __shared__ u16 sA[128 * RS];
  __shared__ u16 sB[128 * RS];
  __shared__ float sq[128];
  int tid = threadIdx.x;
  long row0 = (long)blockIdx.x * 128;
  const float* src;
  u16* dst;
  if (row0 < (long)BB * SS) { src = tgt + row0 * DD; dst = qb + row0 * DD; }
  else { src = memin + (row0 - (long)BB * SS) * DD; dst = kb + (row0 - (long)BB * SS) * DD; }

  for (int p = 0; p < 16; ++p) {
    int r = p * 8 + (tid >> 5);
    int c4 = (tid & 31) * 4;
    float4 v = *(const float4*)(src + r * DD + c4);
    u32 p0 = (u32)f2b(v.x) | ((u32)f2b(v.y) << 16);
    u32 p1 = (u32)f2b(v.z) | ((u32)f2b(v.w) << 16);
    *(u32*)&sA[r * RS + c4] = p0;
    *(u32*)&sA[r * RS + c4 + 2] = p1;
    float4 w = *(const float4*)(w1 + r * DD + c4);
    u32 q0 = (u32)f2b(w.x) | ((u32)f2b(w.y) << 16);
    u32 q1 = (u32)f2b(w.z) | ((u32)f2b(w.w) << 16);
    *(u32*)&sB[r * RS + c4] = q0;
    *(u32*)&sB[r * RS + c4 + 2] = q1;
  }
  if (tid < 128) sq[tid] = 0.f;
  __syncthreads();

  int lane = tid & 63, wv = tid >> 6;
  int wr = wv >> 1, wc = wv & 1;
  int l15 = lane & 15, lg = lane >> 4;

  floatx4 acc[4][4];
  for (int mi = 0; mi < 4; ++mi)
    for (int ni = 0; ni < 4; ++ni) acc[mi][ni] = (floatx4){0.f, 0.f, 0.f, 0.f};

  for (int kc = 0; kc < 4; ++kc) {
    int k0 = kc * 32 + lg * 8;
    short8 af[4], bfr[4];
    for (int mi = 0; mi < 4; ++mi) af[mi] = *(const short8*)&sA[(wr * 64 + mi * 16 + l15) * RS + k0];
    for (int ni = 0; ni < 4; ++ni) bfr[ni] = *(const short8*)&sB[(wc * 64 + ni * 16 + l15) * RS + k0];
    for (int mi = 0; mi < 4; ++mi)
      for (int ni = 0; ni < 4; ++ni)
        acc[mi][ni] = __builtin_amdgcn_mfma_f32_16x16x32_bf16(af[mi], bfr[ni], acc[mi][ni], 0, 0, 0);
  }

  float bvals[4];
  for (int ni = 0; ni < 4; ++ni) bvals[ni] = b1[wc * 64 + ni * 16 + l15];
  for (int mi = 0; mi < 4; ++mi)
    for (int r = 0; r < 4; ++r) {
      float s = 0.f;
      for (int ni = 0; ni < 4; ++ni) {
        float v = acc[mi][ni][r] + bvals[ni];
        acc[mi][ni][r] = v;
        s += v * v;
      }
      s += __shfl_xor(s, 1); s += __shfl_xor(s, 2);
      s += __shfl_xor(s, 4); s += __shfl_xor(s, 8);
      if (l15 == 0) atomicAdd(&sq[wr * 64 + mi * 16 + lg * 4 + r], s);
    }
  __syncthreads();

  for (int mi = 0; mi < 4; ++mi)
    for (int r = 0; r < 4; ++r) {
      int row = wr * 64 + mi * 16 + lg * 4 + r;
      float scale = 1.f / fmaxf(sqrtf(sq[row]), 1e-12f);
      for (int ni = 0; ni < 4; ++ni)
        sA[row * RS + wc * 64 + ni * 16 + l15] = f2b(acc[mi][ni][r] * scale);
    }
  __syncthreads();
  for (int p = 0; p < 16; ++p) {
    int r = p * 8 + (tid >> 5);
    int c4 = (tid & 31) * 4;
    uint2 val = *(const uint2*)&sA[r * RS + c4];
    *(uint2*)(dst + r * DD + c4) = val;
  }
}

// ---------------- K2: one 128x128 attn tile pair per block ----------------
// Q direct to MFMA A-fragments (no LDS), K staged in LDS, bf16 gate in epilogue.
// Block id swizzled so each XCD owns 4 whole batches (L2 locality).
__global__ __launch_bounds__(256, 3) void k_attn(const u16* __restrict__ qb,
                                                 const u16* __restrict__ kb,
                                                 const u16* __restrict__ gTb,
                                                 u32* __restrict__ m1u, u32* __restrict__ m2u) {
  __shared__ u16 sK[128 * RS];
  __shared__ float scmax[2][128];
  __shared__ float srmax[2][128];
  int tid = threadIdx.x;
  int n = blockIdx.x;                 // 5408 = 8 * 676
  int id = (n & 7) * 676 + (n >> 3);  // bijective: XCD c gets ids [c*676, (c+1)*676)
  int b = id / 169;
  int r2 = id - b * 169;
  int sy = r2 / 13, tx = r2 - sy * 13;
  int s0 = min(sy * 128, SS - 128);   // edge tiles clamp-overlap; max is idempotent
  int t0 = min(tx * 128, SS - 128);
  int lane = tid & 63, wv = tid >> 6;
  int wr = wv >> 1, wc = wv & 1;
  int l15 = lane & 15, lg = lane >> 4;
  const size_t base = (size_t)b * SS * DD;

  // Q fragments straight from global (A-layout: row=l15, k=lg*8..+7)
  short8 qf[4][4];
  {
    const u16* qp = qb + base + (size_t)(s0 + wr * 64 + l15) * DD + lg * 8;
    for (int mi = 0; mi < 4; ++mi)
      for (int kc = 0; kc < 4; ++kc)
        qf[mi][kc] = *(const short8*)(qp + mi * 16 * DD + kc * 32);
  }
  // K tile -> LDS
  {
    int rr0 = tid >> 4;
    int c8 = (tid & 15) * 8;
    const u16* kp = kb + base + (size_t)(t0 + rr0) * DD + c8;
    u16* sp = &sK[rr0 * RS + c8];
    for (int p = 0; p < 8; ++p)
      *(uint4*)(sp + p * 16 * RS) = *(const uint4*)(kp + (size_t)p * 16 * DD);
  }
  __syncthreads();

  floatx4 acc[4][4];
  for (int mi = 0; mi < 4; ++mi)
    for (int ni = 0; ni < 4; ++ni) acc[mi][ni] = (floatx4){0.f, 0.f, 0.f, 0.f};
  for (int kc = 0; kc < 4; ++kc) {
    int k0 = kc * 32 + lg * 8;
    short8 bfr[4];
    for (int ni = 0; ni < 4; ++ni) bfr[ni] = *(const short8*)&sK[(wc * 64 + ni * 16 + l15) * RS + k0];
    for (int mi = 0; mi < 4; ++mi)
      for (int ni = 0; ni < 4; ++ni)
        acc[mi][ni] = __builtin_amdgcn_mfma_f32_16x16x32_bf16(qf[mi][kc], bfr[ni], acc[mi][ni], 0, 0, 0);
  }

  // gate multiply (bf16 gate, loaded now so its regs reuse dead qf) + row/col max
  float rmax[4][4];
  for (int mi = 0; mi < 4; ++mi)
    for (int r = 0; r < 4; ++r) rmax[mi][r] = -1e30f;
  float cmax[4];
  for (int ni = 0; ni < 4; ++ni) cmax[ni] = -1e30f;

  int srow0 = s0 + wr * 64 + lg * 4;
  int tc0 = t0 + wc * 64 + l15;
  for (int mi = 0; mi < 4; ++mi)
    for (int ni = 0; ni < 4; ++ni) {
      ushort4 ge = *(const ushort4*)(gTb + (size_t)(tc0 + ni * 16) * SS + srow0 + mi * 16);
      float v0 = acc[mi][ni][0] * b2f(ge.x);
      float v1 = acc[mi][ni][1] * b2f(ge.y);
      float v2 = acc[mi][ni][2] * b2f(ge.z);
      float v3 = acc[mi][ni][3] * b2f(ge.w);
      rmax[mi][0] = fmaxf(rmax[mi][0], v0);
      rmax[mi][1] = fmaxf(rmax[mi][1], v1);
      rmax[mi][2] = fmaxf(rmax[mi][2], v2);
      rmax[mi][3] = fmaxf(rmax[mi][3], v3);
      cmax[ni] = fmaxf(cmax[ni], fmaxf(fmaxf(v0, v1), fmaxf(v2, v3)));
    }

  // column max: reduce over lg (rows)
  for (int ni = 0; ni < 4; ++ni) {
    cmax[ni] = fmaxf(cmax[ni], __shfl_xor(cmax[ni], 16));
    cmax[ni] = fmaxf(cmax[ni], __shfl_xor(cmax[ni], 32));
  }
  if (lane < 16)
    for (int ni = 0; ni < 4; ++ni) scmax[wr][wc * 64 + ni * 16 + l15] = cmax[ni];

  // row max: reduce over l15 (cols)
  for (int mi = 0; mi < 4; ++mi)
    for (int r = 0; r < 4; ++r) {
      float v = rmax[mi][r];
      v = fmaxf(v, __shfl_xor(v, 1));
      v = fmaxf(v, __shfl_xor(v, 2));
      v = fmaxf(v, __shfl_xor(v, 4));
      v = fmaxf(v, __shfl_xor(v, 8));
      if (l15 == 0) srmax[wc][wr * 64 + mi * 16 + lg * 4 + r] = v;
    }
  __syncthreads();

  if (tid < 128) {
    float v = fmaxf(scmax[0][tid], scmax[1][tid]);
    atomicMax(&m1u[b * SS + t0 + tid], encf(v));
  } else {
    int i = tid - 128;
    float v = fmaxf(srmax[0][i], srmax[1][i]);
    atomicMax(&m2u[b * SS + s0 + i], encf(v));
  }
}

// ---------------- K3b: hacc[cs][b][f] = partial(BN1(x) @ w2^T), BN1 fused ----------------
__global__ __launch_bounds__(256) void k_gemm2(const u32* __restrict__ m1u,
                                               const u32* __restrict__ m2u,
                                               const float* __restrict__ g1,
                                               const float* __restrict__ be1,
                                               const float* __restrict__ w2,
                                               float* __restrict__ hacc) {
  int tid = threadIdx.x;
  int lane = tid & 63, wv = tid >> 6;
  int f0 = blockIdx.x * 32 + wv * 8;
  int cs = blockIdx.y;
  int cr0 = cs * 800;
  const u32* msrc = (cs < 2) ? m1u : m2u;
  int mcol0 = cr0 - ((cs < 2) ? 0 : SS);  // column base within msrc
  int c_sub = lane & 15, bq = lane >> 4;
  const float bnc = rsqrtf(1.f + 1e-5f);
  float acc[8][8];
  for (int a = 0; a < 8; ++a)
    for (int c = 0; c < 8; ++c) acc[a][c] = 0.f;
  const float4 z4 = {0.f, 0.f, 0.f, 0.f};
  for (int it = 0; it < 13; ++it) {
    int coff = it * 64 + c_sub * 4;
    bool ok = coff < 800;
    int cg = cr0 + coff;  // global column in [0,3200)
    float4 w4[8], x4[8];
    float4 gv = ok ? *(const float4*)(g1 + cg) : z4;
    float4 bv = ok ? *(const float4*)(be1 + cg) : z4;
    gv.x *= bnc; gv.y *= bnc; gv.z *= bnc; gv.w *= bnc;
    for (int jf = 0; jf < 8; ++jf)
      w4[jf] = ok ? *(const float4*)(w2 + (size_t)(f0 + jf) * S2N + cg) : z4;
    for (int j = 0; j < 8; ++j) {
      if (ok) {
        uint4 e = *(const uint4*)(msrc + (size_t)(bq * 8 + j) * SS + mcol0 + coff);
        x4[j].x = decf(e.x) * gv.x + bv.x;
        x4[j].y = decf(e.y) * gv.y + bv.y;
        x4[j].z = decf(e.z) * gv.z + bv.z;
        x4[j].w = decf(e.w) * gv.w + bv.w;
      } else {
        x4[j] = z4;
      }
    }
    for (int jf = 0; jf < 8; ++jf)
      for (int j = 0; j < 8; ++j) {
        float a = acc[jf][j];
        a = fmaf(w4[jf].x, x4[j].x, a);
        a = fmaf(w4[jf].y, x4[j].y, a);
        a = fmaf(w4[jf].z, x4[j].z, a);
        a = fmaf(w4[jf].w, x4[j].w, a);
        acc[jf][j] = a;
      }
  }
  for (int jf = 0; jf < 8; ++jf)
    for (int j = 0; j < 8; ++j) {
      float v = acc[jf][j];
      v += __shfl_xor(v, 1); v += __shfl_xor(v, 2);
      v += __shfl_xor(v, 4); v += __shfl_xor(v, 8);
      acc[jf][j] = v;
    }
  if ((lane & 15) == 0) {
    for (int jf = 0; jf < 8; ++jf)
      for (int j = 0; j < 8; ++j) {
        int b = bq * 8 + j;
        hacc[((size_t)cs * BB + b) * DFFN + f0 + jf] = acc[jf][j];
      }
  }
}

// ---------------- K3c: BN2 + relu + dot w3 + BN3 ----------------
__global__ __launch_bounds__(256) void k_final(const float* __restrict__ hacc,
                                               const float* __restrict__ b2,
                                               const float* __restrict__ g2,
                                               const float* __restrict__ be2,
                                               const float* __restrict__ w3,
                                               const float* __restrict__ b3,
                                               const float* __restrict__ g3,
                                               const float* __restrict__ be3,
                                               float* __restrict__ out) {
  __shared__ float wsum[4];
  int b = blockIdx.x;
  int tid = threadIdx.x;
  float bnc = rsqrtf(1.f + 1e-5f);
  float part = 0.f;
  for (int f = tid; f < DFFN; f += 256) {
    float s = hacc[((size_t)0 * BB + b) * DFFN + f] + hacc[((size_t)1 * BB + b) * DFFN + f] +
              hacc[((size_t)2 * BB + b) * DFFN + f] + hacc[((size_t)3 * BB + b) * DFFN + f];
    s += b2[f];
    s = s * (g2[f] * bnc) + be2[f];
    s = fmaxf(s, 0.f);
    part += s * w3[f];
  }
  for (int m = 1; m < 64; m <<= 1) part += __shfl_xor(part, m);
  if ((tid & 63) == 0) wsum[tid >> 6] = part;
  __syncthreads();
  if (tid == 0) {
    float tot = wsum[0] + wsum[1] + wsum[2] + wsum[3] + b3[0];
    out[b] = tot * (g3[0] * bnc) + be3[0];
  }
}

extern "C" void kernel_launch(void* const* d_in, const int* in_sizes, int n_in,
                              void* d_out, int out_size, void* d_ws, size_t ws_size,
                              hipStream_t stream) {
  const float* tgt = (const float*)d_in[0];
  const float* memin = (const float*)d_in[1];
  const float* se = (const float*)d_in[2];
  const float* w1 = (const float*)d_in[3];
  const float* b1 = (const float*)d_in[4];
  const float* g1 = (const float*)d_in[5];
  const float* be1 = (const float*)d_in[6];
  const float* w2 = (const float*)d_in[7];
  const float* b2 = (const float*)d_in[8];
  const float* g2 = (const float*)d_in[9];
  const float* be2 = (const float*)d_in[10];
  const float* w3 = (const float*)d_in[11];
  const float* b3 = (const float*)d_in[12];
  const float* g3 = (const float*)d_in[13];
  const float* be3 = (const float*)d_in[14];
  float* out = (float*)d_out;

  char* ws = (char*)d_ws;
  const size_t OFF_GT = 0;                       // bf16 gate: 1600*1600*2 = 5,120,000
  const size_t OFF_QB = 5120000;
  const size_t OFF_KB = OFF_QB + 13107200;
  const size_t OFF_M1 = OFF_KB + 13107200;
  const size_t OFF_M2 = OFF_M1 + 204800;
  const size_t OFF_HA = OFF_M2 + 204800;
  const size_t NEEDED = OFF_HA + (size_t)4 * BB * DFFN * 4;
  if (ws_size < NEEDED) return;  // clean validation failure rather than OOB

  u16* gTb = (u16*)(ws + OFF_GT);
  u16* qb = (u16*)(ws + OFF_QB);
  u16* kb = (u16*)(ws + OFF_KB);
  u32* m1u = (u32*)(ws + OFF_M1);
  u32* m2u = (u32*)(ws + OFF_M2);
  float* hacc = (float*)(ws + OFF_HA);

  k_init<<<625, 256, 0, stream>>>(se, gTb, m1u, m2u);
  k_proj<<<800, 256, 0, stream>>>(tgt, memin, w1, b1, qb, kb);
  k_attn<<<5408, 256, 0, stream>>>(qb, kb, gTb, m1u, m2u);
  k_gemm2<<<dim3(64, 4), 256, 0, stream>>>(m1u, m2u, g1, be1, w2, hacc);
  k_final<<<32, 256, 0, stream>>>(hacc, b2, g2, be2, w3, b3, g3, be3, out);
}

// Round 4
// 166.052 us; speedup vs baseline: 1.1272x; 1.1272x over previous
//
#include <hip/hip_runtime.h>
#include <hip/hip_bf16.h>

#define BB 32
#define SS 1600
#define DD 128
#define DFFN 2048
#define S2N 3200
#define RS 136  // LDS row stride in bf16 elems (128 + 8 pad -> 2-way-max bank aliasing on b128 reads)

typedef __attribute__((ext_vector_type(8))) short short8;
typedef __attribute__((ext_vector_type(4))) float floatx4;
typedef unsigned int u32;
typedef unsigned short u16;

__device__ __forceinline__ u32 encf(float f) {
  u32 u = __float_as_uint(f);
  return (u & 0x80000000u) ? ~u : (u | 0x80000000u);
}
__device__ __forceinline__ float decf(u32 e) {
  u32 u = (e & 0x80000000u) ? (e & 0x7fffffffu) : ~e;
  return __uint_as_float(u);
}
__device__ __forceinline__ u16 f2b(float x) {
  __hip_bfloat16 h = __float2bfloat16(x);
  return __builtin_bit_cast(u16, h);
}
__device__ __forceinline__ float b2f(u16 h) { return __uint_as_float(((u32)h) << 16); }
__device__ __forceinline__ float sigm(float x) { return 1.f / (1.f + __expf(-x)); }

// ---------------- K0: build fragment-ordered bf16 gate tiles; w1->bf16; init m1u/m2u ----------------
// Gate tile layout (per clamped 128x128 tile r2 = sy*13+tx):
//   elem offset = wv*4096 + (mi*4+ni)*256 + lane*4 + r   (u16 elems)
// holding sigmoid(se[s0+wr*64+mi*16+lg*4+r][t0+wc*64+ni*16+l15]),  wv=wr*2+wc, lane=lg*16+l15.
// Exactly the per-lane order k_attn's epilogue consumes -> 512B-contiguous wave loads.
__global__ __launch_bounds__(256) void k_init(const float* __restrict__ se,
                                              u16* __restrict__ gT2,
                                              const float* __restrict__ w1,
                                              u16* __restrict__ w1b,
                                              u32* __restrict__ m1u,
                                              u32* __restrict__ m2u) {
  int tid = threadIdx.x;
  int bid = blockIdx.x;  // 676 blocks
  int i = bid * 256 + tid;
  if (i < BB * SS) {  // 0 encodes "below every finite float" in the monotonic map
    m1u[i] = 0u;
    m2u[i] = 0u;
  }
  if (i < 4096) {  // w1: 16384 floats = 4096 float4
    float4 v = ((const float4*)w1)[i];
    ushort4 o;
    o.x = f2b(v.x); o.y = f2b(v.y); o.z = f2b(v.z); o.w = f2b(v.w);
    ((ushort4*)w1b)[i] = o;
  }
  if (bid < 676) {  // quarter-tile per block: tile r2 = bid>>2, mi = bid&3
    int r2 = bid >> 2, mi = bid & 3;
    int sy = r2 / 13, tx = r2 - sy * 13;
    int s0 = min(sy * 128, SS - 128);
    int t0 = min(tx * 128, SS - 128);
    int lane = tid & 63, wv = tid >> 6;
    int wr = wv >> 1, wc = wv & 1;
    int l15 = lane & 15, lg = lane >> 4;
    int srow = s0 + wr * 64 + mi * 16 + lg * 4;
    u16* tb = gT2 + (size_t)r2 * 16384 + wv * 4096 + mi * 4 * 256 + lane * 4;
    for (int ni = 0; ni < 4; ++ni) {
      int tcol = t0 + wc * 64 + ni * 16 + l15;
      const float* sp = se + (size_t)srow * SS + tcol;
      ushort4 o;
      o.x = f2b(sigm(sp[0]));
      o.y = f2b(sigm(sp[SS]));
      o.z = f2b(sigm(sp[2 * SS]));
      o.w = f2b(sigm(sp[3 * SS]));
      *(ushort4*)(tb + ni * 256) = o;
    }
  }
}

// ---------------- K1: q/k projection + l2norm (bf16 MFMA, w1 direct from bf16 global) ----------------
__global__ __launch_bounds__(256) void k_proj(const float* __restrict__ tgt,
                                              const float* __restrict__ memin,
                                              const u16* __restrict__ w1b,
                                              const float* __restrict__ b1,
                                              u16* __restrict__ qb, u16* __restrict__ kb) {
  __shared__ u16 sA[128 * RS];
  __shared__ float sq[128];
  int tid = threadIdx.x;
  long row0 = (long)blockIdx.x * 128;
  const float* src;
  u16* dst;
  if (row0 < (long)BB * SS) { src = tgt + row0 * DD; dst = qb + row0 * DD; }
  else { src = memin + (row0 - (long)BB * SS) * DD; dst = kb + (row0 - (long)BB * SS) * DD; }

  for (int p = 0; p < 16; ++p) {
    int r = p * 8 + (tid >> 5);
    int c4 = (tid & 31) * 4;
    float4 v = *(const float4*)(src + r * DD + c4);
    u32 p0 = (u32)f2b(v.x) | ((u32)f2b(v.y) << 16);
    u32 p1 = (u32)f2b(v.z) | ((u32)f2b(v.w) << 16);
    *(u32*)&sA[r * RS + c4] = p0;
    *(u32*)&sA[r * RS + c4 + 2] = p1;
  }
  if (tid < 128) sq[tid] = 0.f;
  __syncthreads();

  int lane = tid & 63, wv = tid >> 6;
  int wr = wv >> 1, wc = wv & 1;
  int l15 = lane & 15, lg = lane >> 4;

  floatx4 acc[4][4];
  for (int mi = 0; mi < 4; ++mi)
    for (int ni = 0; ni < 4; ++ni) acc[mi][ni] = (floatx4){0.f, 0.f, 0.f, 0.f};

  for (int kc = 0; kc < 4; ++kc) {
    int k0 = kc * 32 + lg * 8;
    short8 af[4], bfr[4];
    for (int mi = 0; mi < 4; ++mi) af[mi] = *(const short8*)&sA[(wr * 64 + mi * 16 + l15) * RS + k0];
    for (int ni = 0; ni < 4; ++ni)
      bfr[ni] = *(const short8*)(w1b + (size_t)(wc * 64 + ni * 16 + l15) * DD + k0);
    for (int mi = 0; mi < 4; ++mi)
      for (int ni = 0; ni < 4; ++ni)
        acc[mi][ni] = __builtin_amdgcn_mfma_f32_16x16x32_bf16(af[mi], bfr[ni], acc[mi][ni], 0, 0, 0);
  }

  float bvals[4];
  for (int ni = 0; ni < 4; ++ni) bvals[ni] = b1[wc * 64 + ni * 16 + l15];
  for (int mi = 0; mi < 4; ++mi)
    for (int r = 0; r < 4; ++r) {
      float s = 0.f;
      for (int ni = 0; ni < 4; ++ni) {
        float v = acc[mi][ni][r] + bvals[ni];
        acc[mi][ni][r] = v;
        s += v * v;
      }
      s += __shfl_xor(s, 1); s += __shfl_xor(s, 2);
      s += __shfl_xor(s, 4); s += __shfl_xor(s, 8);
      if (l15 == 0) atomicAdd(&sq[wr * 64 + mi * 16 + lg * 4 + r], s);
    }
  __syncthreads();

  for (int mi = 0; mi < 4; ++mi)
    for (int r = 0; r < 4; ++r) {
      int row = wr * 64 + mi * 16 + lg * 4 + r;
      float scale = 1.f / fmaxf(sqrtf(sq[row]), 1e-12f);
      for (int ni = 0; ni < 4; ++ni)
        sA[row * RS + wc * 64 + ni * 16 + l15] = f2b(acc[mi][ni][r] * scale);
    }
  __syncthreads();
  for (int p = 0; p < 16; ++p) {
    int r = p * 8 + (tid >> 5);
    int c4 = (tid & 31) * 4;
    uint2 val = *(const uint2*)&sA[r * RS + c4];
    *(uint2*)(dst + r * DD + c4) = val;
  }
}

// ---------------- K2: one 128x128 attn tile pair per block ----------------
// Q direct to MFMA A-fragments, K via LDS, gate from fragment-ordered tiles
// (512B-contiguous wave loads) issued mid-MFMA so latency hides under MFMAs.
__global__ __launch_bounds__(256, 3) void k_attn(const u16* __restrict__ qb,
                                                 const u16* __restrict__ kb,
                                                 const u16* __restrict__ gT2,
                                                 u32* __restrict__ m1u, u32* __restrict__ m2u) {
  __shared__ u16 sK[128 * RS];
  __shared__ float scmax[2][128];
  __shared__ float srmax[2][128];
  int tid = threadIdx.x;
  int n = blockIdx.x;                 // 5408 = 8 * 676
  int id = (n & 7) * 676 + (n >> 3);  // bijective: XCD c gets ids [c*676, (c+1)*676)
  int b = id / 169;
  int r2 = id - b * 169;
  int sy = r2 / 13, tx = r2 - sy * 13;
  int s0 = min(sy * 128, SS - 128);   // edge tiles clamp-overlap; max is idempotent
  int t0 = min(tx * 128, SS - 128);
  int lane = tid & 63, wv = tid >> 6;
  int wr = wv >> 1, wc = wv & 1;
  int l15 = lane & 15, lg = lane >> 4;
  const size_t base = (size_t)b * SS * DD;

  // Q fragments straight from global (A-layout: row=l15, k=lg*8..+7)
  short8 qf[4][4];
  {
    const u16* qp = qb + base + (size_t)(s0 + wr * 64 + l15) * DD + lg * 8;
    for (int mi = 0; mi < 4; ++mi)
      for (int kc = 0; kc < 4; ++kc)
        qf[mi][kc] = *(const short8*)(qp + mi * 16 * DD + kc * 32);
  }
  // K tile -> LDS
  {
    int rr0 = tid >> 4;
    int c8 = (tid & 15) * 8;
    const u16* kp = kb + base + (size_t)(t0 + rr0) * DD + c8;
    u16* sp = &sK[rr0 * RS + c8];
    for (int p = 0; p < 8; ++p)
      *(uint4*)(sp + p * 16 * RS) = *(const uint4*)(kp + (size_t)p * 16 * DD);
  }
  __syncthreads();

  floatx4 acc[4][4];
  for (int mi = 0; mi < 4; ++mi)
    for (int ni = 0; ni < 4; ++ni) acc[mi][ni] = (floatx4){0.f, 0.f, 0.f, 0.f};

  for (int kc = 0; kc < 2; ++kc) {
    int k0 = kc * 32 + lg * 8;
    short8 bfr[4];
    for (int ni = 0; ni < 4; ++ni) bfr[ni] = *(const short8*)&sK[(wc * 64 + ni * 16 + l15) * RS + k0];
    for (int mi = 0; mi < 4; ++mi)
      for (int ni = 0; ni < 4; ++ni)
        acc[mi][ni] = __builtin_amdgcn_mfma_f32_16x16x32_bf16(qf[mi][kc], bfr[ni], acc[mi][ni], 0, 0, 0);
  }

  // gate fragment loads: 512B contiguous per wave per (mi,ni); hide under remaining 32 MFMAs
  ushort4 gv[4][4];
  {
    const u16* gbase = gT2 + (size_t)r2 * 16384 + wv * 4096 + lane * 4;
    for (int mi = 0; mi < 4; ++mi)
      for (int ni = 0; ni < 4; ++ni)
        gv[mi][ni] = *(const ushort4*)(gbase + (mi * 4 + ni) * 256);
  }

  for (int kc = 2; kc < 4; ++kc) {
    int k0 = kc * 32 + lg * 8;
    short8 bfr[4];
    for (int ni = 0; ni < 4; ++ni) bfr[ni] = *(const short8*)&sK[(wc * 64 + ni * 16 + l15) * RS + k0];
    for (int mi = 0; mi < 4; ++mi)
      for (int ni = 0; ni < 4; ++ni)
        acc[mi][ni] = __builtin_amdgcn_mfma_f32_16x16x32_bf16(qf[mi][kc], bfr[ni], acc[mi][ni], 0, 0, 0);
  }

  // gate multiply + row/col max
  float rmax[4][4];
  for (int mi = 0; mi < 4; ++mi)
    for (int r = 0; r < 4; ++r) rmax[mi][r] = -1e30f;
  float cmax[4];
  for (int ni = 0; ni < 4; ++ni) cmax[ni] = -1e30f;

  for (int mi = 0; mi < 4; ++mi)
    for (int ni = 0; ni < 4; ++ni) {
      ushort4 ge = gv[mi][ni];
      float v0 = acc[mi][ni][0] * b2f(ge.x);
      float v1 = acc[mi][ni][1] * b2f(ge.y);
      float v2 = acc[mi][ni][2] * b2f(ge.z);
      float v3 = acc[mi][ni][3] * b2f(ge.w);
      rmax[mi][0] = fmaxf(rmax[mi][0], v0);
      rmax[mi][1] = fmaxf(rmax[mi][1], v1);
      rmax[mi][2] = fmaxf(rmax[mi][2], v2);
      rmax[mi][3] = fmaxf(rmax[mi][3], v3);
      cmax[ni] = fmaxf(cmax[ni], fmaxf(fmaxf(v0, v1), fmaxf(v2, v3)));
    }

  // column max: reduce over lg (rows)
  for (int ni = 0; ni < 4; ++ni) {
    cmax[ni] = fmaxf(cmax[ni], __shfl_xor(cmax[ni], 16));
    cmax[ni] = fmaxf(cmax[ni], __shfl_xor(cmax[ni], 32));
  }
  if (lane < 16)
    for (int ni = 0; ni < 4; ++ni) scmax[wr][wc * 64 + ni * 16 + l15] = cmax[ni];

  // row max: reduce over l15 (cols)
  for (int mi = 0; mi < 4; ++mi)
    for (int r = 0; r < 4; ++r) {
      float v = rmax[mi][r];
      v = fmaxf(v, __shfl_xor(v, 1));
      v = fmaxf(v, __shfl_xor(v, 2));
      v = fmaxf(v, __shfl_xor(v, 4));
      v = fmaxf(v, __shfl_xor(v, 8));
      if (l15 == 0) srmax[wc][wr * 64 + mi * 16 + lg * 4 + r] = v;
    }
  __syncthreads();

  if (tid < 128) {
    float v = fmaxf(scmax[0][tid], scmax[1][tid]);
    atomicMax(&m1u[b * SS + t0 + tid], encf(v));
  } else {
    int i = tid - 128;
    float v = fmaxf(srmax[0][i], srmax[1][i]);
    atomicMax(&m2u[b * SS + s0 + i], encf(v));
  }
}

// ---------------- K3b: hacc[cs][b][f] = partial(BN1(x) @ w2^T), BN1 fused ----------------
__global__ __launch_bounds__(256) void k_gemm2(const u32* __restrict__ m1u,
                                               const u32* __restrict__ m2u,
                                               const float* __restrict__ g1,
                                               const float* __restrict__ be1,
                                               const float* __restrict__ w2,
                                               float* __restrict__ hacc) {
  int tid = threadIdx.x;
  int lane = tid & 63, wv = tid >> 6;
  int f0 = blockIdx.x * 32 + wv * 8;
  int cs = blockIdx.y;
  int cr0 = cs * 800;
  const u32* msrc = (cs < 2) ? m1u : m2u;
  int mcol0 = cr0 - ((cs < 2) ? 0 : SS);  // column base within msrc
  int c_sub = lane & 15, bq = lane >> 4;
  const float bnc = rsqrtf(1.f + 1e-5f);
  float acc[8][8];
  for (int a = 0; a < 8; ++a)
    for (int c = 0; c < 8; ++c) acc[a][c] = 0.f;
  const float4 z4 = {0.f, 0.f, 0.f, 0.f};
  for (int it = 0; it < 13; ++it) {
    int coff = it * 64 + c_sub * 4;
    bool ok = coff < 800;
    int cg = cr0 + coff;  // global column in [0,3200)
    float4 w4[8], x4[8];
    float4 gv = ok ? *(const float4*)(g1 + cg) : z4;
    float4 bv = ok ? *(const float4*)(be1 + cg) : z4;
    gv.x *= bnc; gv.y *= bnc; gv.z *= bnc; gv.w *= bnc;
    for (int jf = 0; jf < 8; ++jf)
      w4[jf] = ok ? *(const float4*)(w2 + (size_t)(f0 + jf) * S2N + cg) : z4;
    for (int j = 0; j < 8; ++j) {
      if (ok) {
        uint4 e = *(const uint4*)(msrc + (size_t)(bq * 8 + j) * SS + mcol0 + coff);
        x4[j].x = decf(e.x) * gv.x + bv.x;
        x4[j].y = decf(e.y) * gv.y + bv.y;
        x4[j].z = decf(e.z) * gv.z + bv.z;
        x4[j].w = decf(e.w) * gv.w + bv.w;
      } else {
        x4[j] = z4;
      }
    }
    for (int jf = 0; jf < 8; ++jf)
      for (int j = 0; j < 8; ++j) {
        float a = acc[jf][j];
        a = fmaf(w4[jf].x, x4[j].x, a);
        a = fmaf(w4[jf].y, x4[j].y, a);
        a = fmaf(w4[jf].z, x4[j].z, a);
        a = fmaf(w4[jf].w, x4[j].w, a);
        acc[jf][j] = a;
      }
  }
  for (int jf = 0; jf < 8; ++jf)
    for (int j = 0; j < 8; ++j) {
      float v = acc[jf][j];
      v += __shfl_xor(v, 1); v += __shfl_xor(v, 2);
      v += __shfl_xor(v, 4); v += __shfl_xor(v, 8);
      acc[jf][j] = v;
    }
  if ((lane & 15) == 0) {
    for (int jf = 0; jf < 8; ++jf)
      for (int j = 0; j < 8; ++j) {
        int b = bq * 8 + j;
        hacc[((size_t)cs * BB + b) * DFFN + f0 + jf] = acc[jf][j];
      }
  }
}

// ---------------- K3c: BN2 + relu + dot w3 + BN3 ----------------
__global__ __launch_bounds__(256) void k_final(const float* __restrict__ hacc,
                                               const float* __restrict__ b2,
                                               const float* __restrict__ g2,
                                               const float* __restrict__ be2,
                                               const float* __restrict__ w3,
                                               const float* __restrict__ b3,
                                               const float* __restrict__ g3,
                                               const float* __restrict__ be3,
                                               float* __restrict__ out) {
  __shared__ float wsum[4];
  int b = blockIdx.x;
  int tid = threadIdx.x;
  float bnc = rsqrtf(1.f + 1e-5f);
  float part = 0.f;
  for (int f = tid; f < DFFN; f += 256) {
    float s = hacc[((size_t)0 * BB + b) * DFFN + f] + hacc[((size_t)1 * BB + b) * DFFN + f] +
              hacc[((size_t)2 * BB + b) * DFFN + f] + hacc[((size_t)3 * BB + b) * DFFN + f];
    s += b2[f];
    s = s * (g2[f] * bnc) + be2[f];
    s = fmaxf(s, 0.f);
    part += s * w3[f];
  }
  for (int m = 1; m < 64; m <<= 1) part += __shfl_xor(part, m);
  if ((tid & 63) == 0) wsum[tid >> 6] = part;
  __syncthreads();
  if (tid == 0) {
    float tot = wsum[0] + wsum[1] + wsum[2] + wsum[3] + b3[0];
    out[b] = tot * (g3[0] * bnc) + be3[0];
  }
}

extern "C" void kernel_launch(void* const* d_in, const int* in_sizes, int n_in,
                              void* d_out, int out_size, void* d_ws, size_t ws_size,
                              hipStream_t stream) {
  const float* tgt = (const float*)d_in[0];
  const float* memin = (const float*)d_in[1];
  const float* se = (const float*)d_in[2];
  const float* w1 = (const float*)d_in[3];
  const float* b1 = (const float*)d_in[4];
  const float* g1 = (const float*)d_in[5];
  const float* be1 = (const float*)d_in[6];
  const float* w2 = (const float*)d_in[7];
  const float* b2 = (const float*)d_in[8];
  const float* g2 = (const float*)d_in[9];
  const float* be2 = (const float*)d_in[10];
  const float* w3 = (const float*)d_in[11];
  const float* b3 = (const float*)d_in[12];
  const float* g3 = (const float*)d_in[13];
  const float* be3 = (const float*)d_in[14];
  float* out = (float*)d_out;

  char* ws = (char*)d_ws;
  const size_t OFF_GT = 0;                       // tiled bf16 gate: 169*16384*2 = 5,537,792
  const size_t OFF_W1B = 5537792;                // 32 KB
  const size_t OFF_QB = OFF_W1B + 32768;
  const size_t OFF_KB = OFF_QB + 13107200;
  const size_t OFF_M1 = OFF_KB + 13107200;
  const size_t OFF_M2 = OFF_M1 + 204800;
  const size_t OFF_HA = OFF_M2 + 204800;
  const size_t NEEDED = OFF_HA + (size_t)4 * BB * DFFN * 4;
  if (ws_size < NEEDED) return;  // clean validation failure rather than OOB

  u16* gT2 = (u16*)(ws + OFF_GT);
  u16* w1b = (u16*)(ws + OFF_W1B);
  u16* qb = (u16*)(ws + OFF_QB);
  u16* kb = (u16*)(ws + OFF_KB);
  u32* m1u = (u32*)(ws + OFF_M1);
  u32* m2u = (u32*)(ws + OFF_M2);
  float* hacc = (float*)(ws + OFF_HA);

  k_init<<<676, 256, 0, stream>>>(se, gT2, w1, w1b, m1u, m2u);
  k_proj<<<800, 256, 0, stream>>>(tgt, memin, w1b, b1, qb, kb);
  k_attn<<<5408, 256, 0, stream>>>(qb, kb, gT2, m1u, m2u);
  k_gemm2<<<dim3(64, 4), 256, 0, stream>>>(m1u, m2u, g1, be1, w2, hacc);
  k_final<<<32, 256, 0, stream>>>(hacc, b2, g2, be2, w3, b3, g3, be3, out);
}